// Round 1
// baseline (1194.922 us; speedup 1.0000x reference)
//
#include <hip/hip_runtime.h>
#include <hip/hip_bf16.h>

typedef unsigned short u16;
typedef short bf16x8 __attribute__((ext_vector_type(8)));
typedef float f32x4 __attribute__((ext_vector_type(4)));

__device__ __forceinline__ u16 f2b(float f) {
    union { __hip_bfloat16 h; u16 u; } cv;
    cv.h = __float2bfloat16(f);
    return cv.u;
}
__device__ __forceinline__ float b2f(u16 u) {
    union { u16 u; __hip_bfloat16 h; } cv;
    cv.u = u;
    return __bfloat162float(cv.h);
}

// async 16B/lane global->LDS. lds base must be wave-uniform; HW scatters lane i to base + i*16.
__device__ __forceinline__ void g2l16(const void* g, void* l) {
    __builtin_amdgcn_global_load_lds(
        (const __attribute__((address_space(1))) unsigned int*)g,
        (__attribute__((address_space(3))) unsigned int*)l, 16, 0, 0);
}

// ---------------- weight ternarization: per-row absmean + ternary bf16 ----------------
template <int EPT>
__global__ __launch_bounds__(256) void quant_kernel(const float* __restrict__ W,
                                                    u16* __restrict__ T,
                                                    float* __restrict__ scales, int K) {
    const int row = blockIdx.x, tid = threadIdx.x;
    const float* wr = W + (size_t)row * K;
    float v[EPT];
    float s = 0.f;
#pragma unroll
    for (int i = 0; i < EPT; ++i) { v[i] = wr[tid + i * 256]; s += fabsf(v[i]); }
#pragma unroll
    for (int d = 1; d < 64; d <<= 1) s += __shfl_xor(s, d);
    __shared__ float red[4];
    if ((tid & 63) == 0) red[tid >> 6] = s;
    __syncthreads();
    const float absmean = (red[0] + red[1] + red[2] + red[3]) / (float)K;
    const float thr = 0.7f * absmean;
    u16* tr = T + (size_t)row * K;
#pragma unroll
    for (int i = 0; i < EPT; ++i) {
        float w = v[i];
        float t = (fabsf(w) > thr) ? ((w > 0.f) ? 1.f : -1.f) : 0.f;
        tr[tid + i * 256] = f2b(t);
    }
    if (tid == 0) scales[row] = absmean;
}

// ---------------- rmsnorm: fp32 in -> bf16 out, row = 2560 ----------------
__global__ __launch_bounds__(256) void rmsnorm_kernel(const float* __restrict__ x,
                                                      const float* __restrict__ g,
                                                      u16* __restrict__ o) {
    const int row = blockIdx.x, tid = threadIdx.x;
    const float* xr = x + (size_t)row * 2560;
    float v[10];
    float s = 0.f;
#pragma unroll
    for (int i = 0; i < 10; ++i) { v[i] = xr[tid + i * 256]; s += v[i] * v[i]; }
#pragma unroll
    for (int d = 1; d < 64; d <<= 1) s += __shfl_xor(s, d);
    __shared__ float red[4];
    if ((tid & 63) == 0) red[tid >> 6] = s;
    __syncthreads();
    const float total = red[0] + red[1] + red[2] + red[3];
    const float rs = rsqrtf(total * (1.f / 2560.f) + 1e-5f);
    u16* orow = o + (size_t)row * 2560;
#pragma unroll
    for (int i = 0; i < 10; ++i) orow[tid + i * 256] = f2b(v[i] * rs * g[tid + i * 256]);
}

// ---------------- GEMM: C[M,N] = A[M,K](bf16) x B[N,K](bf16 ternary, B^T layout) ----------------
// MODE 0: out bf16 = acc*scale[n].  MODE 1: out fp32 = res + acc*scale[n].
template <int MODE>
__global__ __launch_bounds__(256) void gemm_bt(const u16* __restrict__ A,
                                               const u16* __restrict__ B,
                                               const float* __restrict__ scale,
                                               const float* __restrict__ res,
                                               void* __restrict__ outp,
                                               int M, int N, int K) {
    __shared__ __align__(16) u16 sA[128 * 32];
    __shared__ __align__(16) u16 sB[128 * 32];
    const int tid = threadIdx.x;
    const int wave = tid >> 6, lane = tid & 63;
    const int lane15 = lane & 15, quad = lane >> 4;
    const int m0 = blockIdx.x * 128, n0 = blockIdx.y * 128;
    const int wm = wave >> 1, wn = wave & 1;

    f32x4 acc[4][4] = {};

    // staging: chunk = s*256 + tid (s in {0,1}); row = chunk>>2, col = (chunk&3)*8 elems
    const int r_st = tid >> 2;
    const int c_st = (tid & 3) * 8;
    const size_t a0 = (size_t)(m0 + r_st) * K + c_st;
    const size_t a1 = (size_t)(m0 + 64 + r_st) * K + c_st;
    const size_t b0 = (size_t)(n0 + r_st) * K + c_st;
    const size_t b1 = (size_t)(n0 + 64 + r_st) * K + c_st;
    char* ldsA = (char*)sA + wave * 1024;
    char* ldsB = (char*)sB + wave * 1024;

    for (int kt = 0; kt < K; kt += 32) {
        g2l16(A + a0 + kt, ldsA);
        g2l16(A + a1 + kt, ldsA + 4096);
        g2l16(B + b0 + kt, ldsB);
        g2l16(B + b1 + kt, ldsB + 4096);
        __syncthreads();
        bf16x8 af[4], bfr[4];
#pragma unroll
        for (int f = 0; f < 4; ++f)
            af[f] = *(const bf16x8*)&sA[(wm * 64 + f * 16 + lane15) * 32 + quad * 8];
#pragma unroll
        for (int f = 0; f < 4; ++f)
            bfr[f] = *(const bf16x8*)&sB[(wn * 64 + f * 16 + lane15) * 32 + quad * 8];
#pragma unroll
        for (int i = 0; i < 4; ++i)
#pragma unroll
            for (int j = 0; j < 4; ++j)
                acc[i][j] = __builtin_amdgcn_mfma_f32_16x16x32_bf16(af[i], bfr[j], acc[i][j], 0, 0, 0);
        __syncthreads();
    }

#pragma unroll
    for (int j = 0; j < 4; ++j) {
        const int c = n0 + wn * 64 + j * 16 + lane15;
        const float sc = scale[c];
#pragma unroll
        for (int i = 0; i < 4; ++i) {
            const int rbase = m0 + wm * 64 + i * 16 + quad * 4;
#pragma unroll
            for (int r = 0; r < 4; ++r) {
                const float vv = acc[i][j][r] * sc;
                const size_t idx = (size_t)(rbase + r) * N + c;
                if (MODE == 0) ((u16*)outp)[idx] = f2b(vv);
                else           ((float*)outp)[idx] = res[idx] + vv;
            }
        }
    }
}

// ---------------- RoPE in-place on [2048, nh*128] bf16 ----------------
__global__ __launch_bounds__(256) void rope_kernel(u16* __restrict__ buf,
                                                   const float* __restrict__ cs,
                                                   const float* __restrict__ sn, int nh) {
    const int idx = blockIdx.x * 256 + threadIdx.x;
    const int d = idx & 63;
    const int h = (idx >> 6) % nh;
    const int s = idx / (64 * nh);
    const size_t base = (size_t)s * (nh * 128) + h * 128;
    const float a = b2f(buf[base + d]), b = b2f(buf[base + d + 64]);
    const float c1 = cs[s * 128 + d], s1 = sn[s * 128 + d];
    const float c2 = cs[s * 128 + d + 64], s2 = sn[s * 128 + d + 64];
    buf[base + d] = f2b(a * c1 - b * s1);
    buf[base + d + 64] = f2b(b * c2 + a * s2);
}

// ---------------- V transpose: [2048, 640] -> [5][128][2048] ----------------
__global__ __launch_bounds__(256) void transpose_v_kernel(const u16* __restrict__ V,
                                                          u16* __restrict__ VT) {
    __shared__ u16 t[128 * 66];
    const int tid = threadIdx.x;
    const int h = blockIdx.y, s0 = blockIdx.x * 64;
#pragma unroll
    for (int i = 0; i < 32; ++i) {
        const int idx = tid + i * 256;  // 64 s-rows x 128 d
        const int r = idx >> 7, c = idx & 127;
        t[c * 66 + r] = V[(size_t)(s0 + r) * 640 + h * 128 + c];
    }
    __syncthreads();
#pragma unroll
    for (int i = 0; i < 32; ++i) {
        const int idx = tid + i * 256;  // 128 d-rows x 64 s
        const int d = idx >> 6, s = idx & 63;
        VT[((size_t)h * 128 + d) * 2048 + s0 + s] = t[d * 66 + s];
    }
}

// ---------------- flash attention: 20 heads, GQA 4:1, S=2048, D=128, non-causal ----------------
__global__ __launch_bounds__(256, 2) void flash_kernel(const u16* __restrict__ Q,
                                                       const u16* __restrict__ Kb,
                                                       const u16* __restrict__ VT,
                                                       u16* __restrict__ O) {
    __shared__ __align__(16) u16 sQ[128 * 128];  // Q tile; first 128*64 reused as P
    __shared__ __align__(16) u16 sK[64 * 128];
    __shared__ __align__(16) u16 sV[128 * 64];   // V^T tile [d][key]
    const int tid = threadIdx.x, wave = tid >> 6, lane = tid & 63;
    const int lane15 = lane & 15, quad = lane >> 4;
    const int head = blockIdx.y, q0 = blockIdx.x * 128, kvh = head >> 2;

    {   // stage Q [128][128]
        const int qr = tid >> 4, qc = (tid & 15) * 8;
        char* ldsQ = (char*)sQ + wave * 1024;
#pragma unroll
        for (int s = 0; s < 8; ++s)
            g2l16(Q + (size_t)(q0 + s * 16 + qr) * 2560 + head * 128 + qc, ldsQ + s * 4096);
    }
    __syncthreads();
    bf16x8 qf[2][4];  // wave owns q rows [wave*32, wave*32+32)
#pragma unroll
    for (int mf = 0; mf < 2; ++mf)
#pragma unroll
        for (int kc = 0; kc < 4; ++kc)
            qf[mf][kc] = *(const bf16x8*)&sQ[(wave * 32 + mf * 16 + lane15) * 128 + kc * 32 + quad * 8];

    float m_i[2][4], l_i[2][4];
    f32x4 o_acc[2][8] = {};
#pragma unroll
    for (int a = 0; a < 2; ++a)
#pragma unroll
        for (int b = 0; b < 4; ++b) { m_i[a][b] = -1e30f; l_i[a][b] = 0.f; }

    const int kr = tid >> 4, kc8 = (tid & 15) * 8;
    const int vr = tid >> 3, vc8 = (tid & 7) * 8;
    const u16* vtb = VT + (size_t)kvh * 128 * 2048;
    char* ldsK = (char*)sK + wave * 1024;
    char* ldsV = (char*)sV + wave * 1024;

    for (int k0 = 0; k0 < 2048; k0 += 64) {
#pragma unroll
        for (int s = 0; s < 4; ++s) {
            g2l16(Kb + (size_t)(k0 + s * 16 + kr) * 640 + kvh * 128 + kc8, ldsK + s * 4096);
            g2l16(vtb + (size_t)(s * 32 + vr) * 2048 + k0 + vc8, ldsV + s * 4096);
        }
        __syncthreads();

        // S = Q K^T for this wave's 32 rows x 64 keys
        f32x4 sacc[2][4] = {};
#pragma unroll
        for (int nf = 0; nf < 4; ++nf)
#pragma unroll
            for (int kc = 0; kc < 4; ++kc) {
                const bf16x8 kf = *(const bf16x8*)&sK[(nf * 16 + lane15) * 128 + kc * 32 + quad * 8];
                sacc[0][nf] = __builtin_amdgcn_mfma_f32_16x16x32_bf16(qf[0][kc], kf, sacc[0][nf], 0, 0, 0);
                sacc[1][nf] = __builtin_amdgcn_mfma_f32_16x16x32_bf16(qf[1][kc], kf, sacc[1][nf], 0, 0, 0);
            }

        const float scl = 0.088388347648318447f;  // 1/sqrt(128)
#pragma unroll
        for (int mf = 0; mf < 2; ++mf) {
#pragma unroll
            for (int r = 0; r < 4; ++r) {
                float mx = -1e30f;
#pragma unroll
                for (int nf = 0; nf < 4; ++nf) {
                    sacc[mf][nf][r] *= scl;
                    mx = fmaxf(mx, sacc[mf][nf][r]);
                }
#pragma unroll
                for (int d = 1; d < 16; d <<= 1) mx = fmaxf(mx, __shfl_xor(mx, d));
                const float mnew = fmaxf(m_i[mf][r], mx);
                const float alpha = __expf(m_i[mf][r] - mnew);
                m_i[mf][r] = mnew;
                float sum = 0.f;
#pragma unroll
                for (int nf = 0; nf < 4; ++nf) {
                    const float p = __expf(sacc[mf][nf][r] - mnew);
                    sacc[mf][nf][r] = p;
                    sum += p;
                }
#pragma unroll
                for (int d = 1; d < 16; d <<= 1) sum += __shfl_xor(sum, d);
                l_i[mf][r] = l_i[mf][r] * alpha + sum;
#pragma unroll
                for (int nf = 0; nf < 8; ++nf) o_acc[mf][nf][r] *= alpha;
            }
        }

        // P (C-layout) -> LDS [128][64] (own rows only; same-wave DS ops are ordered)
        u16* sP = sQ;
#pragma unroll
        for (int mf = 0; mf < 2; ++mf)
#pragma unroll
            for (int nf = 0; nf < 4; ++nf)
#pragma unroll
                for (int r = 0; r < 4; ++r)
                    sP[(wave * 32 + mf * 16 + quad * 4 + r) * 64 + nf * 16 + lane15] = f2b(sacc[mf][nf][r]);

        // O += P V
#pragma unroll
        for (int kc = 0; kc < 2; ++kc) {
            bf16x8 pf[2];
#pragma unroll
            for (int mf = 0; mf < 2; ++mf)
                pf[mf] = *(const bf16x8*)&sP[(wave * 32 + mf * 16 + lane15) * 64 + kc * 32 + quad * 8];
#pragma unroll
            for (int nf = 0; nf < 8; ++nf) {
                const bf16x8 vf = *(const bf16x8*)&sV[(nf * 16 + lane15) * 64 + kc * 32 + quad * 8];
                o_acc[0][nf] = __builtin_amdgcn_mfma_f32_16x16x32_bf16(pf[0], vf, o_acc[0][nf], 0, 0, 0);
                o_acc[1][nf] = __builtin_amdgcn_mfma_f32_16x16x32_bf16(pf[1], vf, o_acc[1][nf], 0, 0, 0);
            }
        }
        __syncthreads();
    }

#pragma unroll
    for (int mf = 0; mf < 2; ++mf)
#pragma unroll
        for (int r = 0; r < 4; ++r) {
            const float inv = 1.f / l_i[mf][r];
            const int row = q0 + wave * 32 + mf * 16 + quad * 4 + r;
            u16* orow = O + (size_t)row * 2560 + head * 128;
#pragma unroll
            for (int nf = 0; nf < 8; ++nf)
                orow[nf * 16 + lane15] = f2b(o_acc[mf][nf][r] * inv);
        }
}

// ---------------- t = relu(g)^2 * u, in place over g ----------------
__global__ __launch_bounds__(256) void glu_kernel(u16* __restrict__ g, const u16* __restrict__ u) {
    const size_t i = (size_t)blockIdx.x * 256 + threadIdx.x;
    float gv = b2f(g[i]);
    gv = fmaxf(gv, 0.f);
    g[i] = f2b(gv * gv * b2f(u[i]));
}

extern "C" void kernel_launch(void* const* d_in, const int* in_sizes, int n_in,
                              void* d_out, int out_size, void* d_ws, size_t ws_size,
                              hipStream_t stream) {
    (void)in_sizes; (void)n_in; (void)out_size; (void)ws_size;
    const float* x      = (const float*)d_in[0];
    const float* cosb   = (const float*)d_in[1];
    const float* sinb   = (const float*)d_in[2];
    const float* q_w    = (const float*)d_in[3];
    const float* k_w    = (const float*)d_in[4];
    const float* v_w    = (const float*)d_in[5];
    const float* o_w    = (const float*)d_in[6];
    const float* gate_w = (const float*)d_in[7];
    const float* up_w   = (const float*)d_in[8];
    const float* down_w = (const float*)d_in[9];
    const float* ln1    = (const float*)d_in[10];
    const float* ln2    = (const float*)d_in[11];

    char* w = (char*)d_ws;
    size_t off = 0;
    auto nxt = [&](size_t sz) { char* p = w + off; off += sz; return p; };
    u16*   TQ = (u16*)nxt(13107200);   // q ternary  [2560,2560]
    u16*   TK = (u16*)nxt(3276800);    // k ternary  [640,2560]
    u16*   TV = (u16*)nxt(3276800);    // v ternary  [640,2560]
    u16*   TO = (u16*)nxt(13107200);   // o ternary  [2560,2560]
    u16*   TB = (u16*)nxt(35389440);   // shared big ternary (gate/up/down, quantized just-in-time)
    float* SC = (float*)nxt(91136);    // scales: q@0 k@2560 v@3200 o@3840 g@6400 u@13312 d@20224
    u16*   H  = (u16*)nxt(10485760);   // rmsnorm out bf16 [2048,2560]; reused as attn out and h2
    u16*   QB = (u16*)nxt(10485760);   // q proj bf16 [2048,2560]
    u16*   KB = (u16*)nxt(2621440);    // k proj bf16 [2048,640]
    u16*   VB = (u16*)nxt(2621440);    // v proj bf16 [2048,640]
    u16*   VT = (u16*)nxt(2621440);    // v transposed [5][128][2048]
    float* XM = (float*)nxt(20971520); // x after o-proj residual, fp32 [2048,2560]
    u16*   G  = (u16*)nxt(28311552);   // gate out bf16 [2048,6912]; becomes t in place
    u16*   U  = TQ;                    // up out reuses TQ..TO span (32.7MB >= 28.3MB, free by then)

    // --- attention path ---
    quant_kernel<10><<<2560, 256, 0, stream>>>(q_w, TQ, SC + 0, 2560);
    quant_kernel<10><<<640, 256, 0, stream>>>(k_w, TK, SC + 2560, 2560);
    quant_kernel<10><<<640, 256, 0, stream>>>(v_w, TV, SC + 3200, 2560);
    quant_kernel<10><<<2560, 256, 0, stream>>>(o_w, TO, SC + 3840, 2560);
    rmsnorm_kernel<<<2048, 256, 0, stream>>>(x, ln1, H);
    gemm_bt<0><<<dim3(16, 20), 256, 0, stream>>>(H, TQ, SC + 0, nullptr, QB, 2048, 2560, 2560);
    gemm_bt<0><<<dim3(16, 5), 256, 0, stream>>>(H, TK, SC + 2560, nullptr, KB, 2048, 640, 2560);
    gemm_bt<0><<<dim3(16, 5), 256, 0, stream>>>(H, TV, SC + 3200, nullptr, VB, 2048, 640, 2560);
    rope_kernel<<<10240, 256, 0, stream>>>(QB, cosb, sinb, 20);
    rope_kernel<<<2560, 256, 0, stream>>>(KB, cosb, sinb, 5);
    transpose_v_kernel<<<dim3(32, 5), 256, 0, stream>>>(VB, VT);
    flash_kernel<<<dim3(16, 20), 256, 0, stream>>>(QB, KB, VT, H);
    gemm_bt<1><<<dim3(16, 20), 256, 0, stream>>>(H, TO, SC + 3840, x, XM, 2048, 2560, 2560);

    // --- MLP path ---
    rmsnorm_kernel<<<2048, 256, 0, stream>>>(XM, ln2, H);
    quant_kernel<10><<<6912, 256, 0, stream>>>(gate_w, TB, SC + 6400, 2560);
    gemm_bt<0><<<dim3(16, 54), 256, 0, stream>>>(H, TB, SC + 6400, nullptr, G, 2048, 6912, 2560);
    quant_kernel<10><<<6912, 256, 0, stream>>>(up_w, TB, SC + 13312, 2560);
    gemm_bt<0><<<dim3(16, 54), 256, 0, stream>>>(H, TB, SC + 13312, nullptr, U, 2048, 6912, 2560);
    glu_kernel<<<55296, 256, 0, stream>>>(G, U);
    quant_kernel<27><<<2560, 256, 0, stream>>>(down_w, TB, SC + 20224, 6912);
    gemm_bt<1><<<dim3(16, 20), 256, 0, stream>>>(G, TB, SC + 20224, XM, (float*)d_out, 2048, 2560, 6912);
}

// Round 2
// 1003.382 us; speedup vs baseline: 1.1909x; 1.1909x over previous
//
#include <hip/hip_runtime.h>
#include <hip/hip_bf16.h>

typedef unsigned short u16;
typedef short bf16x8 __attribute__((ext_vector_type(8)));
typedef float f32x4 __attribute__((ext_vector_type(4)));

__device__ __forceinline__ u16 f2b(float f) {
    union { __hip_bfloat16 h; u16 u; } cv;
    cv.h = __float2bfloat16(f);
    return cv.u;
}
__device__ __forceinline__ float b2f(u16 u) {
    union { u16 u; __hip_bfloat16 h; } cv;
    cv.u = u;
    return __bfloat162float(cv.h);
}

// async 16B/lane global->LDS. lds base must be wave-uniform; HW scatters lane i to base + i*16.
__device__ __forceinline__ void g2l16(const void* g, void* l) {
    __builtin_amdgcn_global_load_lds(
        (const __attribute__((address_space(1))) unsigned int*)g,
        (__attribute__((address_space(3))) unsigned int*)l, 16, 0, 0);
}

// ---------------- weight ternarization: per-row absmean + ternary bf16 ----------------
template <int EPT>
__global__ __launch_bounds__(256) void quant_kernel(const float* __restrict__ W,
                                                    u16* __restrict__ T,
                                                    float* __restrict__ scales, int K) {
    const int row = blockIdx.x, tid = threadIdx.x;
    const float* wr = W + (size_t)row * K;
    float v[EPT];
    float s = 0.f;
#pragma unroll
    for (int i = 0; i < EPT; ++i) { v[i] = wr[tid + i * 256]; s += fabsf(v[i]); }
#pragma unroll
    for (int d = 1; d < 64; d <<= 1) s += __shfl_xor(s, d);
    __shared__ float red[4];
    if ((tid & 63) == 0) red[tid >> 6] = s;
    __syncthreads();
    const float absmean = (red[0] + red[1] + red[2] + red[3]) / (float)K;
    const float thr = 0.7f * absmean;
    u16* tr = T + (size_t)row * K;
#pragma unroll
    for (int i = 0; i < EPT; ++i) {
        float w = v[i];
        float t = (fabsf(w) > thr) ? ((w > 0.f) ? 1.f : -1.f) : 0.f;
        tr[tid + i * 256] = f2b(t);
    }
    if (tid == 0) scales[row] = absmean;
}

// ---------------- rmsnorm: fp32 in -> bf16 out, row = 2560 ----------------
__global__ __launch_bounds__(256) void rmsnorm_kernel(const float* __restrict__ x,
                                                      const float* __restrict__ g,
                                                      u16* __restrict__ o) {
    const int row = blockIdx.x, tid = threadIdx.x;
    const float* xr = x + (size_t)row * 2560;
    float v[10];
    float s = 0.f;
#pragma unroll
    for (int i = 0; i < 10; ++i) { v[i] = xr[tid + i * 256]; s += v[i] * v[i]; }
#pragma unroll
    for (int d = 1; d < 64; d <<= 1) s += __shfl_xor(s, d);
    __shared__ float red[4];
    if ((tid & 63) == 0) red[tid >> 6] = s;
    __syncthreads();
    const float total = red[0] + red[1] + red[2] + red[3];
    const float rs = rsqrtf(total * (1.f / 2560.f) + 1e-5f);
    u16* orow = o + (size_t)row * 2560;
#pragma unroll
    for (int i = 0; i < 10; ++i) orow[tid + i * 256] = f2b(v[i] * rs * g[tid + i * 256]);
}

// ---------------- GEMM: C[M,N] = A[M,K](bf16) x B[N,K](bf16 ternary, B^T layout) ----------------
// BK=64, chunk-XOR-swizzled LDS (conflict-free ds_read_b128 fragments).
// LDS element (row, k) lives at row*64 + ((k>>3) ^ (row&7))*8 + (k&7).
// MODE 0: out bf16 = acc*scale[n].  MODE 1: out fp32 = res + acc*scale[n].
template <int MODE>
__global__ __launch_bounds__(256) void gemm_bt(const u16* __restrict__ A,
                                               const u16* __restrict__ B,
                                               const float* __restrict__ scale,
                                               const float* __restrict__ res,
                                               void* __restrict__ outp,
                                               int M, int N, int K) {
    __shared__ __align__(16) u16 sA[128 * 64];
    __shared__ __align__(16) u16 sB[128 * 64];
    const int tid = threadIdx.x;
    const int wave = tid >> 6, lane = tid & 63;
    const int lane15 = lane & 15, quad = lane >> 4;
    const int m0 = blockIdx.x * 128, n0 = blockIdx.y * 128;
    const int wm = wave >> 1, wn = wave & 1;

    f32x4 acc[4][4] = {};

    // staging: instr s covers LDS chunks [s*256, s*256+256); chunk = s*256 + wave*64 + lane
    // row = s*32 + wave*8 + (lane>>3); phys chunk-in-row = lane&7; global chunk = (lane&7)^(row&7)
    const int r0 = wave * 8 + (lane >> 3);           // 0..31, row&7 == lane>>3
    const int gcc = (lane & 7) ^ (lane >> 3);
    const size_t aoff = (size_t)(m0 + r0) * K + gcc * 8;
    const size_t boff = (size_t)(n0 + r0) * K + gcc * 8;
    char* ldsA = (char*)sA + wave * 1024;
    char* ldsB = (char*)sB + wave * 1024;
    const int sw = lane15 & 7;  // fragment-read swizzle key (row&7 == lane15&7)

    for (int kt = 0; kt < K; kt += 64) {
#pragma unroll
        for (int s = 0; s < 4; ++s) {
            g2l16(A + aoff + (size_t)s * 32 * K + kt, ldsA + s * 4096);
            g2l16(B + boff + (size_t)s * 32 * K + kt, ldsB + s * 4096);
        }
        __syncthreads();
#pragma unroll
        for (int kc = 0; kc < 2; ++kc) {
            bf16x8 af[4], bfr[4];
            const int pc = ((kc * 4 + quad) ^ sw) * 8;
#pragma unroll
            for (int f = 0; f < 4; ++f)
                af[f] = *(const bf16x8*)&sA[(wm * 64 + f * 16 + lane15) * 64 + pc];
#pragma unroll
            for (int f = 0; f < 4; ++f)
                bfr[f] = *(const bf16x8*)&sB[(wn * 64 + f * 16 + lane15) * 64 + pc];
#pragma unroll
            for (int i = 0; i < 4; ++i)
#pragma unroll
                for (int j = 0; j < 4; ++j)
                    acc[i][j] = __builtin_amdgcn_mfma_f32_16x16x32_bf16(af[i], bfr[j], acc[i][j], 0, 0, 0);
        }
        __syncthreads();
    }

#pragma unroll
    for (int j = 0; j < 4; ++j) {
        const int c = n0 + wn * 64 + j * 16 + lane15;
        const float sc = scale[c];
#pragma unroll
        for (int i = 0; i < 4; ++i) {
            const int rbase = m0 + wm * 64 + i * 16 + quad * 4;
#pragma unroll
            for (int r = 0; r < 4; ++r) {
                const float vv = acc[i][j][r] * sc;
                const size_t idx = (size_t)(rbase + r) * N + c;
                if (MODE == 0) ((u16*)outp)[idx] = f2b(vv);
                else           ((float*)outp)[idx] = res[idx] + vv;
            }
        }
    }
}

// ---------------- RoPE in-place on [2048, nh*128] bf16 ----------------
__global__ __launch_bounds__(256) void rope_kernel(u16* __restrict__ buf,
                                                   const float* __restrict__ cs,
                                                   const float* __restrict__ sn, int nh) {
    const int idx = blockIdx.x * 256 + threadIdx.x;
    const int d = idx & 63;
    const int h = (idx >> 6) % nh;
    const int s = idx / (64 * nh);
    const size_t base = (size_t)s * (nh * 128) + h * 128;
    const float a = b2f(buf[base + d]), b = b2f(buf[base + d + 64]);
    const float c1 = cs[s * 128 + d], s1 = sn[s * 128 + d];
    const float c2 = cs[s * 128 + d + 64], s2 = sn[s * 128 + d + 64];
    buf[base + d] = f2b(a * c1 - b * s1);
    buf[base + d + 64] = f2b(b * c2 + a * s2);
}

// ---------------- V transpose: [2048, 640] -> [5][128][2048] ----------------
__global__ __launch_bounds__(256) void transpose_v_kernel(const u16* __restrict__ V,
                                                          u16* __restrict__ VT) {
    __shared__ u16 t[128 * 66];
    const int tid = threadIdx.x;
    const int h = blockIdx.y, s0 = blockIdx.x * 64;
#pragma unroll
    for (int i = 0; i < 32; ++i) {
        const int idx = tid + i * 256;  // 64 s-rows x 128 d
        const int r = idx >> 7, c = idx & 127;
        t[c * 66 + r] = V[(size_t)(s0 + r) * 640 + h * 128 + c];
    }
    __syncthreads();
#pragma unroll
    for (int i = 0; i < 32; ++i) {
        const int idx = tid + i * 256;  // 128 d-rows x 64 s
        const int d = idx >> 6, s = idx & 63;
        VT[((size_t)h * 128 + d) * 2048 + s0 + s] = t[d * 66 + s];
    }
}

// ---------------- flash attention: 20 heads, GQA 4:1, S=2048, D=128, non-causal ----------------
// 64 q-rows/block (wave owns 16), 64-key tiles, swizzled LDS, exp2-domain online softmax.
__global__ __launch_bounds__(256, 3) void flash_kernel(const u16* __restrict__ Q,
                                                       const u16* __restrict__ Kb,
                                                       const u16* __restrict__ VT,
                                                       u16* __restrict__ O) {
    __shared__ __align__(16) u16 sQ[64 * 128];  // 16 KB; reused as sP (64x64) after qf loaded
    __shared__ __align__(16) u16 sK[64 * 128];  // 16 KB
    __shared__ __align__(16) u16 sV[128 * 64];  // 16 KB, V^T tile [d][key]
    const int tid = threadIdx.x, wave = tid >> 6, lane = tid & 63;
    const int lane15 = lane & 15, quad = lane >> 4;
    const int head = blockIdx.y, q0 = blockIdx.x * 64, kvh = head >> 2;
    const int sw = lane15 & 7;

    {   // stage Q: 4 instrs x 16 rows; wave covers rows wave*4 + (lane>>4) (+s*16)
        const int rq = wave * 4 + (lane >> 4);
        const int gq = (lane & 15) ^ (rq & 7);
        const u16* src = Q + (size_t)(q0 + rq) * 2560 + head * 128 + gq * 8;
        char* dst = (char*)sQ + wave * 1024;
#pragma unroll
        for (int s = 0; s < 4; ++s)
            g2l16(src + (size_t)s * 16 * 2560, dst + s * 4096);
    }
    __syncthreads();
    bf16x8 qf[4];
#pragma unroll
    for (int kc = 0; kc < 4; ++kc)
        qf[kc] = *(const bf16x8*)&sQ[(wave * 16 + lane15) * 128 + ((kc * 4 + quad) ^ sw) * 8];

    float m_i[4], l_i[4];
    f32x4 o_acc[8] = {};
#pragma unroll
    for (int r = 0; r < 4; ++r) { m_i[r] = -1e30f; l_i[r] = 0.f; }

    const float sl2e = 0.088388347648318447f * 1.4426950408889634f;  // 1/sqrt(128) * log2(e)

    // staging addresses
    const int rk = wave * 4 + (lane >> 4);
    const int gk = (lane & 15) ^ (rk & 7);
    const u16* kbase = Kb + (size_t)rk * 640 + kvh * 128 + gk * 8;
    const int rv = wave * 8 + (lane >> 3);
    const int gv = (lane & 7) ^ (rv & 7);
    const u16* vbase = VT + ((size_t)kvh * 128 + rv) * 2048 + gv * 8;
    char* dstK = (char*)sK + wave * 1024;
    char* dstV = (char*)sV + wave * 1024;
    u16* sP = sQ;

    for (int k0 = 0; k0 < 2048; k0 += 64) {
#pragma unroll
        for (int s = 0; s < 4; ++s) {
            g2l16(kbase + ((size_t)k0 + s * 16) * 640, dstK + s * 4096);
            g2l16(vbase + (size_t)s * 32 * 2048 + k0, dstV + s * 4096);
        }
        __syncthreads();

        // S = Q K^T : wave's 16 q-rows x 64 keys
        f32x4 sacc[4] = {};
#pragma unroll
        for (int nf = 0; nf < 4; ++nf)
#pragma unroll
            for (int kc = 0; kc < 4; ++kc) {
                const bf16x8 kf = *(const bf16x8*)&sK[(nf * 16 + lane15) * 128 + ((kc * 4 + quad) ^ sw) * 8];
                sacc[nf] = __builtin_amdgcn_mfma_f32_16x16x32_bf16(qf[kc], kf, sacc[nf], 0, 0, 0);
            }

        // online softmax in exp2 domain; row r of this lane = quad*4+r, key = nf*16+lane15
#pragma unroll
        for (int r = 0; r < 4; ++r) {
            float v0 = sacc[0][r] * sl2e, v1 = sacc[1][r] * sl2e;
            float v2 = sacc[2][r] * sl2e, v3 = sacc[3][r] * sl2e;
            float mx = fmaxf(fmaxf(v0, v1), fmaxf(v2, v3));
#pragma unroll
            for (int d = 1; d < 16; d <<= 1) mx = fmaxf(mx, __shfl_xor(mx, d));
            const float mnew = fmaxf(m_i[r], mx);
            const float alpha = exp2f(m_i[r] - mnew);
            m_i[r] = mnew;
            const float p0 = exp2f(v0 - mnew), p1 = exp2f(v1 - mnew);
            const float p2 = exp2f(v2 - mnew), p3 = exp2f(v3 - mnew);
            sacc[0][r] = p0; sacc[1][r] = p1; sacc[2][r] = p2; sacc[3][r] = p3;
            float sum = (p0 + p1) + (p2 + p3);
#pragma unroll
            for (int d = 1; d < 16; d <<= 1) sum += __shfl_xor(sum, d);
            l_i[r] = l_i[r] * alpha + sum;
#pragma unroll
            for (int nf = 0; nf < 8; ++nf) o_acc[nf][r] *= alpha;
        }

        // P -> sP (own 16 rows; same-wave DS ops are ordered). Quad-swizzled chunks.
#pragma unroll
        for (int nf = 0; nf < 4; ++nf) {
            const int cc = nf * 2 + (lane15 >> 3);
            const int pcol = ((cc ^ quad) * 8) + (lane15 & 7);
#pragma unroll
            for (int r = 0; r < 4; ++r)
                sP[(wave * 16 + quad * 4 + r) * 64 + pcol] = f2b(sacc[nf][r]);
        }

        // O += P V (reads own rows of sP + shared sV)
        bf16x8 pf[2];
#pragma unroll
        for (int kc = 0; kc < 2; ++kc)
            pf[kc] = *(const bf16x8*)&sP[(wave * 16 + lane15) * 64 + ((kc * 4 + quad) ^ ((lane15 >> 2) & 3)) * 8];
#pragma unroll
        for (int nf = 0; nf < 8; ++nf)
#pragma unroll
            for (int kc = 0; kc < 2; ++kc) {
                const bf16x8 vf = *(const bf16x8*)&sV[(nf * 16 + lane15) * 64 + ((kc * 4 + quad) ^ sw) * 8];
                o_acc[nf] = __builtin_amdgcn_mfma_f32_16x16x32_bf16(pf[kc], vf, o_acc[nf], 0, 0, 0);
            }
        __syncthreads();
    }

#pragma unroll
    for (int r = 0; r < 4; ++r) {
        const float inv = 1.f / l_i[r];
        const int row = q0 + wave * 16 + quad * 4 + r;
        u16* orow = O + (size_t)row * 2560 + head * 128;
#pragma unroll
        for (int nf = 0; nf < 8; ++nf)
            orow[nf * 16 + lane15] = f2b(o_acc[nf][r] * inv);
    }
}

// ---------------- t = relu(g)^2 * u, in place over g (8 elems/thread) ----------------
__global__ __launch_bounds__(256) void glu_kernel(u16* __restrict__ g, const u16* __restrict__ u) {
    const size_t i = ((size_t)blockIdx.x * 256 + threadIdx.x) * 8;
    bf16x8 gv = *(const bf16x8*)(g + i);
    bf16x8 uv = *(const bf16x8*)(u + i);
    bf16x8 ov;
#pragma unroll
    for (int j = 0; j < 8; ++j) {
        float x = b2f((u16)gv[j]);
        x = fmaxf(x, 0.f);
        ov[j] = (short)f2b(x * x * b2f((u16)uv[j]));
    }
    *(bf16x8*)(g + i) = ov;
}

extern "C" void kernel_launch(void* const* d_in, const int* in_sizes, int n_in,
                              void* d_out, int out_size, void* d_ws, size_t ws_size,
                              hipStream_t stream) {
    (void)in_sizes; (void)n_in; (void)out_size; (void)ws_size;
    const float* x      = (const float*)d_in[0];
    const float* cosb   = (const float*)d_in[1];
    const float* sinb   = (const float*)d_in[2];
    const float* q_w    = (const float*)d_in[3];
    const float* k_w    = (const float*)d_in[4];
    const float* v_w    = (const float*)d_in[5];
    const float* o_w    = (const float*)d_in[6];
    const float* gate_w = (const float*)d_in[7];
    const float* up_w   = (const float*)d_in[8];
    const float* down_w = (const float*)d_in[9];
    const float* ln1    = (const float*)d_in[10];
    const float* ln2    = (const float*)d_in[11];

    char* w = (char*)d_ws;
    size_t off = 0;
    auto nxt = [&](size_t sz) { char* p = w + off; off += sz; return p; };
    u16*   TQ = (u16*)nxt(13107200);   // q ternary  [2560,2560]
    u16*   TK = (u16*)nxt(3276800);    // k ternary  [640,2560]
    u16*   TV = (u16*)nxt(3276800);    // v ternary  [640,2560]
    u16*   TO = (u16*)nxt(13107200);   // o ternary  [2560,2560]
    u16*   TB = (u16*)nxt(35389440);   // shared big ternary (gate/up/down, quantized just-in-time)
    float* SC = (float*)nxt(91136);    // scales: q@0 k@2560 v@3200 o@3840 g@6400 u@13312 d@20224
    u16*   H  = (u16*)nxt(10485760);   // rmsnorm out bf16 [2048,2560]; reused as attn out and h2
    u16*   QB = (u16*)nxt(10485760);   // q proj bf16 [2048,2560]
    u16*   KB = (u16*)nxt(2621440);    // k proj bf16 [2048,640]
    u16*   VB = (u16*)nxt(2621440);    // v proj bf16 [2048,640]
    u16*   VT = (u16*)nxt(2621440);    // v transposed [5][128][2048]
    float* XM = (float*)nxt(20971520); // x after o-proj residual, fp32 [2048,2560]
    u16*   G  = (u16*)nxt(28311552);   // gate out bf16 [2048,6912]; becomes t in place
    u16*   U  = TQ;                    // up out reuses TQ..TO span (32.7MB >= 28.3MB, free by then)

    // --- attention path ---
    quant_kernel<10><<<2560, 256, 0, stream>>>(q_w, TQ, SC + 0, 2560);
    quant_kernel<10><<<640, 256, 0, stream>>>(k_w, TK, SC + 2560, 2560);
    quant_kernel<10><<<640, 256, 0, stream>>>(v_w, TV, SC + 3200, 2560);
    quant_kernel<10><<<2560, 256, 0, stream>>>(o_w, TO, SC + 3840, 2560);
    rmsnorm_kernel<<<2048, 256, 0, stream>>>(x, ln1, H);
    gemm_bt<0><<<dim3(16, 20), 256, 0, stream>>>(H, TQ, SC + 0, nullptr, QB, 2048, 2560, 2560);
    gemm_bt<0><<<dim3(16, 5), 256, 0, stream>>>(H, TK, SC + 2560, nullptr, KB, 2048, 640, 2560);
    gemm_bt<0><<<dim3(16, 5), 256, 0, stream>>>(H, TV, SC + 3200, nullptr, VB, 2048, 640, 2560);
    rope_kernel<<<10240, 256, 0, stream>>>(QB, cosb, sinb, 20);
    rope_kernel<<<2560, 256, 0, stream>>>(KB, cosb, sinb, 5);
    transpose_v_kernel<<<dim3(32, 5), 256, 0, stream>>>(VB, VT);
    flash_kernel<<<dim3(32, 20), 256, 0, stream>>>(QB, KB, VT, H);
    gemm_bt<1><<<dim3(16, 20), 256, 0, stream>>>(H, TO, SC + 3840, x, XM, 2048, 2560, 2560);

    // --- MLP path ---
    rmsnorm_kernel<<<2048, 256, 0, stream>>>(XM, ln2, H);
    quant_kernel<10><<<6912, 256, 0, stream>>>(gate_w, TB, SC + 6400, 2560);
    gemm_bt<0><<<dim3(16, 54), 256, 0, stream>>>(H, TB, SC + 6400, nullptr, G, 2048, 6912, 2560);
    quant_kernel<10><<<6912, 256, 0, stream>>>(up_w, TB, SC + 13312, 2560);
    gemm_bt<0><<<dim3(16, 54), 256, 0, stream>>>(H, TB, SC + 13312, nullptr, U, 2048, 6912, 2560);
    glu_kernel<<<6912, 256, 0, stream>>>(G, U);
    quant_kernel<27><<<2560, 256, 0, stream>>>(down_w, TB, SC + 20224, 6912);
    gemm_bt<1><<<dim3(16, 20), 256, 0, stream>>>(G, TB, SC + 20224, XM, (float*)d_out, 2048, 2560, 6912);
}

// Round 4
// 852.170 us; speedup vs baseline: 1.4022x; 1.1774x over previous
//
#include <hip/hip_runtime.h>
#include <hip/hip_bf16.h>

typedef unsigned short u16;
typedef short bf16x8 __attribute__((ext_vector_type(8)));
typedef float f32x4 __attribute__((ext_vector_type(4)));

__device__ __forceinline__ u16 f2b(float f) {
    union { __hip_bfloat16 h; u16 u; } cv;
    cv.h = __float2bfloat16(f);
    return cv.u;
}
__device__ __forceinline__ float b2f(u16 u) {
    union { u16 u; __hip_bfloat16 h; } cv;
    cv.u = u;
    return __bfloat162float(cv.h);
}

// async 16B/lane global->LDS. lds base must be wave-uniform; HW scatters lane i to base + i*16.
__device__ __forceinline__ void g2l16(const void* g, void* l) {
    __builtin_amdgcn_global_load_lds(
        (const __attribute__((address_space(1))) unsigned int*)g,
        (__attribute__((address_space(3))) unsigned int*)l, 16, 0, 0);
}

// ---------------- weight ternarization: per-row absmean + ternary bf16 ----------------
template <int EPT>
__global__ __launch_bounds__(256) void quant_kernel(const float* __restrict__ W,
                                                    u16* __restrict__ T,
                                                    float* __restrict__ scales, int K) {
    const int row = blockIdx.x, tid = threadIdx.x;
    const float* wr = W + (size_t)row * K;
    float v[EPT];
    float s = 0.f;
#pragma unroll
    for (int i = 0; i < EPT; ++i) { v[i] = wr[tid + i * 256]; s += fabsf(v[i]); }
#pragma unroll
    for (int d = 1; d < 64; d <<= 1) s += __shfl_xor(s, d);
    __shared__ float red[4];
    if ((tid & 63) == 0) red[tid >> 6] = s;
    __syncthreads();
    const float absmean = (red[0] + red[1] + red[2] + red[3]) / (float)K;
    const float thr = 0.7f * absmean;
    u16* tr = T + (size_t)row * K;
#pragma unroll
    for (int i = 0; i < EPT; ++i) {
        float w = v[i];
        float t = (fabsf(w) > thr) ? ((w > 0.f) ? 1.f : -1.f) : 0.f;
        tr[tid + i * 256] = f2b(t);
    }
    if (tid == 0) scales[row] = absmean;
}

// ---------------- rmsnorm: fp32 in -> bf16 out, row = 2560 ----------------
__global__ __launch_bounds__(256) void rmsnorm_kernel(const float* __restrict__ x,
                                                      const float* __restrict__ g,
                                                      u16* __restrict__ o) {
    const int row = blockIdx.x, tid = threadIdx.x;
    const float* xr = x + (size_t)row * 2560;
    float v[10];
    float s = 0.f;
#pragma unroll
    for (int i = 0; i < 10; ++i) { v[i] = xr[tid + i * 256]; s += v[i] * v[i]; }
#pragma unroll
    for (int d = 1; d < 64; d <<= 1) s += __shfl_xor(s, d);
    __shared__ float red[4];
    if ((tid & 63) == 0) red[tid >> 6] = s;
    __syncthreads();
    const float total = red[0] + red[1] + red[2] + red[3];
    const float rs = rsqrtf(total * (1.f / 2560.f) + 1e-5f);
    u16* orow = o + (size_t)row * 2560;
#pragma unroll
    for (int i = 0; i < 10; ++i) orow[tid + i * 256] = f2b(v[i] * rs * g[tid + i * 256]);
}

// ---------------- GEMM: C[M,N] = A[M,K](bf16) x B[N,K](bf16 ternary, B^T layout) ----------------
// 512 threads, 128x128 tile, BK=64, wave sub-tile 64x32 (acc = 32 AGPR -> 4 waves/SIMD,
// 2 blocks/CU). Chunk-XOR-swizzled LDS: elem (row,k) at row*64 + ((k>>3)^(row&7))*8 + (k&7).
// Staging: one g2l16 instruction = 512 lanes x 16 B = 8192 B = 64 rows; second half at +8192 B.
// MODE 0: out bf16 = acc*scale[n].  MODE 1: out fp32 = res + acc*scale[n].
template <int MODE>
__global__ __launch_bounds__(512, 4) void gemm_bt(const u16* __restrict__ A,
                                                  const u16* __restrict__ B,
                                                  const float* __restrict__ scale,
                                                  const float* __restrict__ res,
                                                  void* __restrict__ outp,
                                                  int M, int N, int K) {
    __shared__ __align__(16) u16 sA[128 * 64];
    __shared__ __align__(16) u16 sB[128 * 64];
    const int tid = threadIdx.x;
    const int wave = tid >> 6, lane = tid & 63;
    const int lane15 = lane & 15, quad = lane >> 4;
    const int m0 = blockIdx.x * 128, n0 = blockIdx.y * 128;
    const int wm = wave >> 2, wn = wave & 3;  // wave tile: rows wm*64+, cols wn*32+

    f32x4 acc[4][2] = {};

    // staging: instr s covers 64 rows; chunk = s*512 + wave*64 + lane
    // row = s*64 + wave*8 + (lane>>3); phys chunk = lane&7; global chunk = (lane&7)^(row&7)
    const int r0 = wave * 8 + (lane >> 3);           // row&7 == lane>>3
    const int gcc = (lane & 7) ^ (lane >> 3);
    const size_t aoff = (size_t)(m0 + r0) * K + gcc * 8;
    const size_t boff = (size_t)(n0 + r0) * K + gcc * 8;
    char* ldsA = (char*)sA + wave * 1024;
    char* ldsB = (char*)sB + wave * 1024;
    const int sw = lane15 & 7;  // fragment-read swizzle key (row&7 == lane15&7)

    for (int kt = 0; kt < K; kt += 64) {
        g2l16(A + aoff + kt, ldsA);
        g2l16(A + aoff + (size_t)64 * K + kt, ldsA + 8192);
        g2l16(B + boff + kt, ldsB);
        g2l16(B + boff + (size_t)64 * K + kt, ldsB + 8192);
        __syncthreads();
#pragma unroll
        for (int kc = 0; kc < 2; ++kc) {
            const int pc = ((kc * 4 + quad) ^ sw) * 8;
            bf16x8 af[4], bfr[2];
#pragma unroll
            for (int f = 0; f < 4; ++f)
                af[f] = *(const bf16x8*)&sA[(wm * 64 + f * 16 + lane15) * 64 + pc];
#pragma unroll
            for (int f = 0; f < 2; ++f)
                bfr[f] = *(const bf16x8*)&sB[(wn * 32 + f * 16 + lane15) * 64 + pc];
#pragma unroll
            for (int i = 0; i < 4; ++i)
#pragma unroll
                for (int j = 0; j < 2; ++j)
                    acc[i][j] = __builtin_amdgcn_mfma_f32_16x16x32_bf16(af[i], bfr[j], acc[i][j], 0, 0, 0);
        }
        __syncthreads();
    }

#pragma unroll
    for (int j = 0; j < 2; ++j) {
        const int c = n0 + wn * 32 + j * 16 + lane15;
        const float sc = scale[c];
#pragma unroll
        for (int i = 0; i < 4; ++i) {
            const int rbase = m0 + wm * 64 + i * 16 + quad * 4;
#pragma unroll
            for (int r = 0; r < 4; ++r) {
                const float vv = acc[i][j][r] * sc;
                const size_t idx = (size_t)(rbase + r) * N + c;
                if (MODE == 0) ((u16*)outp)[idx] = f2b(vv);
                else           ((float*)outp)[idx] = res[idx] + vv;
            }
        }
    }
}

// ---------------- RoPE in-place on [2048, stride] bf16, nh heads at given base ----------------
__global__ __launch_bounds__(256) void rope_kernel(u16* __restrict__ buf, int stride,
                                                   const float* __restrict__ cs,
                                                   const float* __restrict__ sn, int nh) {
    const int idx = blockIdx.x * 256 + threadIdx.x;
    const int d = idx & 63;
    const int h = (idx >> 6) % nh;
    const int s = idx / (64 * nh);
    const size_t base = (size_t)s * stride + h * 128;
    const float a = b2f(buf[base + d]), b = b2f(buf[base + d + 64]);
    const float c1 = cs[s * 128 + d], s1 = sn[s * 128 + d];
    const float c2 = cs[s * 128 + d + 64], s2 = sn[s * 128 + d + 64];
    buf[base + d] = f2b(a * c1 - b * s1);
    buf[base + d + 64] = f2b(b * c2 + a * s2);
}

// ---------------- V transpose: [2048, stride] (head h at col h*128) -> [5][128][2048] ----------------
__global__ __launch_bounds__(256) void transpose_v_kernel(const u16* __restrict__ V, int stride,
                                                          u16* __restrict__ VT) {
    __shared__ u16 t[128 * 66];
    const int tid = threadIdx.x;
    const int h = blockIdx.y, s0 = blockIdx.x * 64;
#pragma unroll
    for (int i = 0; i < 32; ++i) {
        const int idx = tid + i * 256;  // 64 s-rows x 128 d
        const int r = idx >> 7, c = idx & 127;
        t[c * 66 + r] = V[(size_t)(s0 + r) * stride + h * 128 + c];
    }
    __syncthreads();
#pragma unroll
    for (int i = 0; i < 32; ++i) {
        const int idx = tid + i * 256;  // 128 d-rows x 64 s
        const int d = idx >> 6, s = idx & 63;
        VT[((size_t)h * 128 + d) * 2048 + s0 + s] = t[d * 66 + s];
    }
}

// ---------------- flash attention: 20 heads, GQA 4:1, S=2048, D=128, non-causal ----------------
// 64 q-rows/block (wave owns 16), 64-key tiles, swizzled LDS, exp2-domain online softmax.
// Q rows have stride qs (col 0); K rows stride qs at base Kb.
__global__ __launch_bounds__(256, 3) void flash_kernel(const u16* __restrict__ Q, int qs,
                                                       const u16* __restrict__ Kb,
                                                       const u16* __restrict__ VT,
                                                       u16* __restrict__ O) {
    __shared__ __align__(16) u16 sQ[64 * 128];  // 16 KB; reused as sP (64x64) after qf loaded
    __shared__ __align__(16) u16 sK[64 * 128];  // 16 KB
    __shared__ __align__(16) u16 sV[128 * 64];  // 16 KB, V^T tile [d][key]
    const int tid = threadIdx.x, wave = tid >> 6, lane = tid & 63;
    const int lane15 = lane & 15, quad = lane >> 4;
    const int head = blockIdx.y, q0 = blockIdx.x * 64, kvh = head >> 2;
    const int sw = lane15 & 7;

    {   // stage Q: 4 instrs x 16 rows; wave covers rows wave*4 + (lane>>4) (+s*16)
        const int rq = wave * 4 + (lane >> 4);
        const int gq = (lane & 15) ^ (rq & 7);
        const u16* src = Q + (size_t)(q0 + rq) * qs + head * 128 + gq * 8;
        char* dst = (char*)sQ + wave * 1024;
#pragma unroll
        for (int s = 0; s < 4; ++s)
            g2l16(src + (size_t)s * 16 * qs, dst + s * 4096);
    }
    __syncthreads();
    bf16x8 qf[4];
#pragma unroll
    for (int kc = 0; kc < 4; ++kc)
        qf[kc] = *(const bf16x8*)&sQ[(wave * 16 + lane15) * 128 + ((kc * 4 + quad) ^ sw) * 8];

    float m_i[4], l_i[4];
    f32x4 o_acc[8] = {};
#pragma unroll
    for (int r = 0; r < 4; ++r) { m_i[r] = -1e30f; l_i[r] = 0.f; }

    const float sl2e = 0.088388347648318447f * 1.4426950408889634f;  // 1/sqrt(128) * log2(e)

    // staging addresses
    const int rk = wave * 4 + (lane >> 4);
    const int gk = (lane & 15) ^ (rk & 7);
    const u16* kbase = Kb + (size_t)rk * qs + kvh * 128 + gk * 8;
    const int rv = wave * 8 + (lane >> 3);
    const int gv = (lane & 7) ^ (rv & 7);
    const u16* vbase = VT + ((size_t)kvh * 128 + rv) * 2048 + gv * 8;
    char* dstK = (char*)sK + wave * 1024;
    char* dstV = (char*)sV + wave * 1024;
    u16* sP = sQ;

    for (int k0 = 0; k0 < 2048; k0 += 64) {
#pragma unroll
        for (int s = 0; s < 4; ++s) {
            g2l16(kbase + ((size_t)k0 + s * 16) * qs, dstK + s * 4096);
            g2l16(vbase + (size_t)s * 32 * 2048 + k0, dstV + s * 4096);
        }
        __syncthreads();

        // S = Q K^T : wave's 16 q-rows x 64 keys
        f32x4 sacc[4] = {};
#pragma unroll
        for (int nf = 0; nf < 4; ++nf)
#pragma unroll
            for (int kc = 0; kc < 4; ++kc) {
                const bf16x8 kf = *(const bf16x8*)&sK[(nf * 16 + lane15) * 128 + ((kc * 4 + quad) ^ sw) * 8];
                sacc[nf] = __builtin_amdgcn_mfma_f32_16x16x32_bf16(qf[kc], kf, sacc[nf], 0, 0, 0);
            }

        // online softmax in exp2 domain; row r of this lane = quad*4+r, key = nf*16+lane15
#pragma unroll
        for (int r = 0; r < 4; ++r) {
            float v0 = sacc[0][r] * sl2e, v1 = sacc[1][r] * sl2e;
            float v2 = sacc[2][r] * sl2e, v3 = sacc[3][r] * sl2e;
            float mx = fmaxf(fmaxf(v0, v1), fmaxf(v2, v3));
#pragma unroll
            for (int d = 1; d < 16; d <<= 1) mx = fmaxf(mx, __shfl_xor(mx, d));
            const float mnew = fmaxf(m_i[r], mx);
            const float alpha = exp2f(m_i[r] - mnew);
            m_i[r] = mnew;
            const float p0 = exp2f(v0 - mnew), p1 = exp2f(v1 - mnew);
            const float p2 = exp2f(v2 - mnew), p3 = exp2f(v3 - mnew);
            sacc[0][r] = p0; sacc[1][r] = p1; sacc[2][r] = p2; sacc[3][r] = p3;
            float sum = (p0 + p1) + (p2 + p3);
#pragma unroll
            for (int d = 1; d < 16; d <<= 1) sum += __shfl_xor(sum, d);
            l_i[r] = l_i[r] * alpha + sum;
#pragma unroll
            for (int nf = 0; nf < 8; ++nf) o_acc[nf][r] *= alpha;
        }

        // P -> sP (own 16 rows; same-wave DS ops are ordered). Quad-swizzled chunks.
#pragma unroll
        for (int nf = 0; nf < 4; ++nf) {
            const int cc = nf * 2 + (lane15 >> 3);
            const int pcol = ((cc ^ quad) * 8) + (lane15 & 7);
#pragma unroll
            for (int r = 0; r < 4; ++r)
                sP[(wave * 16 + quad * 4 + r) * 64 + pcol] = f2b(sacc[nf][r]);
        }

        // O += P V (reads own rows of sP + shared sV)
        bf16x8 pf[2];
#pragma unroll
        for (int kc = 0; kc < 2; ++kc)
            pf[kc] = *(const bf16x8*)&sP[(wave * 16 + lane15) * 64 + ((kc * 4 + quad) ^ ((lane15 >> 2) & 3)) * 8];
#pragma unroll
        for (int nf = 0; nf < 8; ++nf)
#pragma unroll
            for (int kc = 0; kc < 2; ++kc) {
                const bf16x8 vf = *(const bf16x8*)&sV[(nf * 16 + lane15) * 64 + ((kc * 4 + quad) ^ sw) * 8];
                o_acc[nf] = __builtin_amdgcn_mfma_f32_16x16x32_bf16(pf[kc], vf, o_acc[nf], 0, 0, 0);
            }
        __syncthreads();
    }

#pragma unroll
    for (int r = 0; r < 4; ++r) {
        const float inv = 1.f / l_i[r];
        const int row = q0 + wave * 16 + quad * 4 + r;
        u16* orow = O + (size_t)row * 2560 + head * 128;
#pragma unroll
        for (int nf = 0; nf < 8; ++nf)
            orow[nf * 16 + lane15] = f2b(o_acc[nf][r] * inv);
    }
}

// ---------------- t = relu(g)^2 * u, in place over g (8 elems/thread) ----------------
__global__ __launch_bounds__(256) void glu_kernel(u16* __restrict__ g, const u16* __restrict__ u) {
    const size_t i = ((size_t)blockIdx.x * 256 + threadIdx.x) * 8;
    bf16x8 gv = *(const bf16x8*)(g + i);
    bf16x8 uv = *(const bf16x8*)(u + i);
    bf16x8 ov;
#pragma unroll
    for (int j = 0; j < 8; ++j) {
        float x = b2f((u16)gv[j]);
        x = fmaxf(x, 0.f);
        ov[j] = (short)f2b(x * x * b2f((u16)uv[j]));
    }
    *(bf16x8*)(g + i) = ov;
}

extern "C" void kernel_launch(void* const* d_in, const int* in_sizes, int n_in,
                              void* d_out, int out_size, void* d_ws, size_t ws_size,
                              hipStream_t stream) {
    (void)in_sizes; (void)n_in; (void)out_size; (void)ws_size;
    const float* x      = (const float*)d_in[0];
    const float* cosb   = (const float*)d_in[1];
    const float* sinb   = (const float*)d_in[2];
    const float* q_w    = (const float*)d_in[3];
    const float* k_w    = (const float*)d_in[4];
    const float* v_w    = (const float*)d_in[5];
    const float* o_w    = (const float*)d_in[6];
    const float* gate_w = (const float*)d_in[7];
    const float* up_w   = (const float*)d_in[8];
    const float* down_w = (const float*)d_in[9];
    const float* ln1    = (const float*)d_in[10];
    const float* ln2    = (const float*)d_in[11];

    char* w = (char*)d_ws;
    size_t off = 0;
    auto nxt = [&](size_t sz) { char* p = w + off; off += sz; return p; };
    u16*   TQ = (u16*)nxt(13107200);   // q ternary  [2560,2560]   } contiguous => fused
    u16*   TK = (u16*)nxt(3276800);    // k ternary  [640,2560]    }  qkv B-matrix
    u16*   TV = (u16*)nxt(3276800);    // v ternary  [640,2560]    }  [3840,2560]
    u16*   TO = (u16*)nxt(13107200);   // o ternary  [2560,2560]
    u16*   TB = (u16*)nxt(35389440);   // shared big ternary (gate/up/down, quantized just-in-time)
    float* SC = (float*)nxt(91136);    // scales: q@0 k@2560 v@3200 o@3840 g@6400 u@13312 d@20224
    u16*   H  = (u16*)nxt(10485760);   // rmsnorm out bf16 [2048,2560]; reused as attn out and h2
    u16*   QKV = (u16*)nxt(15728640);  // fused qkv proj bf16 [2048,3840] (q|k|v per row)
    u16*   VT = (u16*)nxt(2621440);    // v transposed [5][128][2048]
    float* XM = (float*)nxt(20971520); // x after o-proj residual, fp32 [2048,2560]
    u16*   G  = (u16*)nxt(28311552);   // gate out bf16 [2048,6912]; becomes t in place
    u16*   U  = TQ;                    // up out reuses TQ..TO span (32.7MB >= 28.3MB, free by then)

    // --- attention path ---
    quant_kernel<10><<<2560, 256, 0, stream>>>(q_w, TQ, SC + 0, 2560);
    quant_kernel<10><<<640, 256, 0, stream>>>(k_w, TK, SC + 2560, 2560);
    quant_kernel<10><<<640, 256, 0, stream>>>(v_w, TV, SC + 3200, 2560);
    quant_kernel<10><<<2560, 256, 0, stream>>>(o_w, TO, SC + 3840, 2560);
    rmsnorm_kernel<<<2048, 256, 0, stream>>>(x, ln1, H);
    gemm_bt<0><<<dim3(16, 30), 512, 0, stream>>>(H, TQ, SC + 0, nullptr, QKV, 2048, 3840, 2560);
    rope_kernel<<<10240, 256, 0, stream>>>(QKV, 3840, cosb, sinb, 20);           // q cols 0..2559
    rope_kernel<<<2560, 256, 0, stream>>>(QKV + 2560, 3840, cosb, sinb, 5);      // k cols 2560..3199
    transpose_v_kernel<<<dim3(32, 5), 256, 0, stream>>>(QKV + 3200, 3840, VT);   // v cols 3200..3839
    flash_kernel<<<dim3(32, 20), 256, 0, stream>>>(QKV, 3840, QKV + 2560, VT, H);
    gemm_bt<1><<<dim3(16, 20), 512, 0, stream>>>(H, TO, SC + 3840, x, XM, 2048, 2560, 2560);

    // --- MLP path ---
    rmsnorm_kernel<<<2048, 256, 0, stream>>>(XM, ln2, H);
    quant_kernel<10><<<6912, 256, 0, stream>>>(gate_w, TB, SC + 6400, 2560);
    gemm_bt<0><<<dim3(16, 54), 512, 0, stream>>>(H, TB, SC + 6400, nullptr, G, 2048, 6912, 2560);
    quant_kernel<10><<<6912, 256, 0, stream>>>(up_w, TB, SC + 13312, 2560);
    gemm_bt<0><<<dim3(16, 54), 512, 0, stream>>>(H, TB, SC + 13312, nullptr, U, 2048, 6912, 2560);
    glu_kernel<<<6912, 256, 0, stream>>>(G, U);
    quant_kernel<27><<<2560, 256, 0, stream>>>(down_w, TB, SC + 20224, 6912);
    gemm_bt<1><<<dim3(16, 20), 512, 0, stream>>>(G, TB, SC + 20224, XM, (float*)d_out, 2048, 2560, 6912);
}